// Round 1
// baseline (233.770 us; speedup 1.0000x reference)
//
#include <hip/hip_runtime.h>

typedef short bf8 __attribute__((ext_vector_type(8)));   // 8 bf16 in 4 VGPRs
typedef float f32x4 __attribute__((ext_vector_type(4)));

__device__ __forceinline__ ushort f2b(float f) {
  unsigned x = __builtin_bit_cast(unsigned, f);
  unsigned r = (x + 0x7fffu + ((x >> 16) & 1u)) >> 16;
  return (ushort)r;
}
__device__ __forceinline__ float b2f(ushort u) {
  unsigned x = ((unsigned)u) << 16;
  return __builtin_bit_cast(float, x);
}

__device__ __forceinline__ f32x4 mfma16(bf8 a, bf8 b, f32x4 c) {
  return __builtin_amdgcn_mfma_f32_16x16x32_bf16(a, b, c, 0, 0, 0);
}

__device__ __forceinline__ void gload16(const ushort* g, ushort* l) {
  __builtin_amdgcn_global_load_lds(
      (const __attribute__((address_space(1))) void*)g,
      (__attribute__((address_space(3))) void*)l, 16, 0, 0);
}

// ---------------- cast x (f32 -> bf16) ----------------
__global__ __launch_bounds__(256) void cast_x(const float* __restrict__ in,
                                              ushort* __restrict__ out) {
  const int i = (blockIdx.x * 256 + threadIdx.x) * 4;
  float4 v = *(const float4*)(in + i);
  ushort4 o;
  o.x = f2b(v.x); o.y = f2b(v.y); o.z = f2b(v.z); o.w = f2b(v.w);
  *(ushort4*)(out + i) = o;
}

// ------- transpose weight [K=1024][N] f32 -> [N][1024] bf16 -------
__global__ void trans_w(const float* __restrict__ in, ushort* __restrict__ out,
                        int N) {
  __shared__ float tile[32][33];
  const int kx = blockIdx.x * 32, nx = blockIdx.y * 32;
  const int tx = threadIdx.x, ty = threadIdx.y;
#pragma unroll
  for (int i = ty; i < 32; i += 8)
    tile[i][tx] = in[(size_t)(kx + i) * N + nx + tx];
  __syncthreads();
#pragma unroll
  for (int i = ty; i < 32; i += 8)
    out[(size_t)(nx + i) * 1024 + kx + tx] = f2b(tile[tx][i]);
}

// ---------------- GEMM C[M][N] = A[M][K] * Bt[N][K]^T ----------------
template <bool OUT_BF16>
__global__ __launch_bounds__(256) void gemm_bt(const ushort* __restrict__ A,
                                               const ushort* __restrict__ Bt,
                                               void* __restrict__ Cv, int M,
                                               int N, int K) {
  __shared__ ushort aL[128 * 32];
  __shared__ ushort bL[128 * 32];
  const int tid = threadIdx.x;
  const int wid = tid >> 6, lane = tid & 63;
  const int l15 = lane & 15, l4 = lane >> 4;
  const int bm = blockIdx.y * 128, bn = blockIdx.x * 128;
  const int wr = (wid >> 1) * 64, wc = (wid & 1) * 64;
  f32x4 acc[4][4] = {};
  for (int kb = 0; kb < K; kb += 32) {
    __syncthreads();
#pragma unroll
    for (int i = 0; i < 2; ++i) {
      const int e = (i * 256 + tid) * 8;
      const int r = e >> 5, c = e & 31;
      gload16(A + (size_t)(bm + r) * K + kb + c, &aL[i * 2048 + wid * 512]);
      gload16(Bt + (size_t)(bn + r) * K + kb + c, &bL[i * 2048 + wid * 512]);
    }
    asm volatile("s_waitcnt vmcnt(0)" ::: "memory");
    __syncthreads();
    bf8 af[4], bfr[4];
#pragma unroll
    for (int i = 0; i < 4; ++i) {
      af[i] = *(const bf8*)&aL[(wr + i * 16 + l15) * 32 + l4 * 8];
      bfr[i] = *(const bf8*)&bL[(wc + i * 16 + l15) * 32 + l4 * 8];
    }
#pragma unroll
    for (int i = 0; i < 4; ++i)
#pragma unroll
      for (int j = 0; j < 4; ++j)
        acc[i][j] = mfma16(af[i], bfr[j], acc[i][j]);
  }
#pragma unroll
  for (int i = 0; i < 4; ++i)
#pragma unroll
    for (int j = 0; j < 4; ++j)
#pragma unroll
      for (int r = 0; r < 4; ++r) {
        const size_t row = bm + wr + i * 16 + l4 * 4 + r;
        const size_t col = bn + wc + j * 16 + l15;
        if constexpr (OUT_BF16)
          ((ushort*)Cv)[row * N + col] = f2b(acc[i][j][r]);
        else
          ((float*)Cv)[row * N + col] = acc[i][j][r];
      }
}

// ---------------- RoPE for Q,K (reads fused qkv bf16) ----------------
// qkv: [4096][1536]; cols 0..1023 = Q (h*64+d), 1024..1279 = K (kv*64+d)
// qh: [b*16+h][2048][64] (Q pre-scaled by 0.125), kh: [b*4+kv][2048][64]
__global__ __launch_bounds__(256) void rope_qk(const ushort* __restrict__ qkv,
                                               const float* __restrict__ fc,
                                               const float* __restrict__ fs,
                                               ushort* __restrict__ qh,
                                               ushort* __restrict__ kh) {
  const int idx = blockIdx.x * 256 + threadIdx.x;  // 4096*640 total
  const int u = idx % 640;
  const int m = idx / 640;
  const int s = m & 2047, b = m >> 11;
  int col, j;
  if (u < 512) {
    j = u & 31;
    col = (u >> 5) * 64 + 2 * j;
  } else {
    j = (u - 512) & 31;
    col = 1024 + ((u - 512) >> 5) * 64 + 2 * j;
  }
  const uint pr = *(const uint*)(qkv + (size_t)m * 1536 + col);
  const float tr = b2f((ushort)(pr & 0xffff));
  const float ti = b2f((ushort)(pr >> 16));
  const float c = fc[s * 32 + j], sn = fs[s * 32 + j];
  float orr = tr * c - ti * sn;
  float oi = tr * sn + ti * c;
  if (u < 512) {
    orr *= 0.125f;  // fold 1/sqrt(64) into Q
    oi *= 0.125f;
    const uint w = (uint)f2b(orr) | ((uint)f2b(oi) << 16);
    *(uint*)(qh + ((size_t)(b * 16 + (u >> 5)) * 2048 + s) * 64 + 2 * j) = w;
  } else {
    const uint w = (uint)f2b(orr) | ((uint)f2b(oi) << 16);
    const int kv = (u - 512) >> 5;
    *(uint*)(kh + ((size_t)(b * 4 + kv) * 2048 + s) * 64 + 2 * j) = w;
  }
}

// ---------------- V transpose: qkv cols 1280.. -> vT[b*4+kv][64][2048] ----
__global__ __launch_bounds__(256) void vtrans(const ushort* __restrict__ qkv,
                                              ushort* __restrict__ vT) {
  __shared__ ushort tile[64][65];
  const int id = blockIdx.x;  // B*KVH*32 = 256
  const int st = id & 31, kv = (id >> 5) & 3, b = id >> 7;
  const int tid = threadIdx.x;
  for (int e = tid; e < 4096; e += 256) {
    const int r = e >> 6, c = e & 63;
    tile[r][c] =
        qkv[(size_t)(b * 2048 + st * 64 + r) * 1536 + 1280 + kv * 64 + c];
  }
  __syncthreads();
  for (int e = tid; e < 4096; e += 256) {
    const int d = e >> 6, c = e & 63;
    vT[((size_t)(b * 4 + kv) * 64 + d) * 2048 + st * 64 + c] = tile[c][d];
  }
}

// ---------------- Flash attention (causal, GQA) ----------------
// grid: (32 = B*H, 32 = S/64), block 256 (4 waves, 16 q-rows per wave)
__global__ __launch_bounds__(256) void attn_fwd(const ushort* __restrict__ qh,
                                                const ushort* __restrict__ kh,
                                                const ushort* __restrict__ vT,
                                                ushort* __restrict__ ao) {
  __shared__ ushort p_lds[4][512];  // per-wave 16x32 P scratch
  const int tid = threadIdx.x;
  const int wid = tid >> 6, lane = tid & 63;
  const int l15 = lane & 15, l4 = lane >> 4;
  const int bh = blockIdx.x;
  const int b = bh >> 4, h = bh & 15;
  const int kv = h >> 2;
  const int qb = blockIdx.y * 64 + wid * 16;

  const ushort* qbase = qh + ((size_t)bh * 2048 + qb + l15) * 64;
  const bf8 qf0 = *(const bf8*)(qbase + l4 * 8);
  const bf8 qf1 = *(const bf8*)(qbase + 32 + l4 * 8);

  const ushort* kbase = kh + (size_t)(b * 4 + kv) * 2048 * 64;
  const ushort* vbase = vT + (size_t)(b * 4 + kv) * 64 * 2048;

  f32x4 acc[4] = {};
  float mreg[4] = {-3e38f, -3e38f, -3e38f, -3e38f};
  float ls[4] = {0.f, 0.f, 0.f, 0.f};

  const int nkb = (qb + 15) >> 5;
  for (int kb = 0; kb <= nkb; ++kb) {
    const int k0 = kb * 32;
    const ushort* kr0 = kbase + (size_t)(k0 + l15) * 64 + l4 * 8;
    const ushort* kr1 = kr0 + 16 * 64;
    const bf8 kf00 = *(const bf8*)(kr0);
    const bf8 kf01 = *(const bf8*)(kr0 + 32);
    const bf8 kf10 = *(const bf8*)(kr1);
    const bf8 kf11 = *(const bf8*)(kr1 + 32);
    f32x4 s0 = {}, s1 = {};
    s0 = mfma16(qf0, kf00, s0);
    s0 = mfma16(qf1, kf01, s0);
    s1 = mfma16(qf0, kf10, s1);
    s1 = mfma16(qf1, kf11, s1);
    if (k0 + 31 > qb) {  // causal boundary tile
#pragma unroll
      for (int r = 0; r < 4; ++r) {
        const int rw = qb + l4 * 4 + r;
        if (k0 + l15 > rw) s0[r] = -1e30f;
        if (k0 + 16 + l15 > rw) s1[r] = -1e30f;
      }
    }
    float mx[4], sm[4], scl[4];
#pragma unroll
    for (int r = 0; r < 4; ++r) mx[r] = fmaxf(s0[r], s1[r]);
#pragma unroll
    for (int d = 1; d < 16; d <<= 1)
#pragma unroll
      for (int r = 0; r < 4; ++r) mx[r] = fmaxf(mx[r], __shfl_xor(mx[r], d));
#pragma unroll
    for (int r = 0; r < 4; ++r) {
      const float mn = fmaxf(mreg[r], mx[r]);
      scl[r] = __expf(mreg[r] - mn);
      mreg[r] = mn;
    }
#pragma unroll
    for (int r = 0; r < 4; ++r) {
      s0[r] = __expf(s0[r] - mreg[r]);
      s1[r] = __expf(s1[r] - mreg[r]);
      sm[r] = s0[r] + s1[r];
    }
#pragma unroll
    for (int d = 1; d < 16; d <<= 1)
#pragma unroll
      for (int r = 0; r < 4; ++r) sm[r] += __shfl_xor(sm[r], d);
#pragma unroll
    for (int r = 0; r < 4; ++r) ls[r] = ls[r] * scl[r] + sm[r];
#pragma unroll
    for (int dt = 0; dt < 4; ++dt)
#pragma unroll
      for (int r = 0; r < 4; ++r) acc[dt][r] *= scl[r];

    // P (C/D layout) -> LDS -> A-fragment layout
    asm volatile("s_waitcnt lgkmcnt(0)" ::: "memory");
#pragma unroll
    for (int r = 0; r < 4; ++r) {
      p_lds[wid][(l4 * 4 + r) * 32 + l15] = f2b(s0[r]);
      p_lds[wid][(l4 * 4 + r) * 32 + 16 + l15] = f2b(s1[r]);
    }
    asm volatile("s_waitcnt lgkmcnt(0)" ::: "memory");
    __builtin_amdgcn_sched_barrier(0);
    const bf8 pa = *(const bf8*)&p_lds[wid][l15 * 32 + l4 * 8];
#pragma unroll
    for (int dt = 0; dt < 4; ++dt) {
      const bf8 vf =
          *(const bf8*)(vbase + (size_t)(dt * 16 + l15) * 2048 + k0 + l4 * 8);
      acc[dt] = mfma16(pa, vf, acc[dt]);
    }
  }
#pragma unroll
  for (int r = 0; r < 4; ++r) {
    const float inv = 1.0f / ls[r];
    const size_t mrow = (size_t)(b * 2048 + qb + l4 * 4 + r) * 1024 + h * 64;
#pragma unroll
    for (int dt = 0; dt < 4; ++dt)
      ao[mrow + dt * 16 + l15] = f2b(acc[dt][r] * inv);
  }
}

extern "C" void kernel_launch(void* const* d_in, const int* in_sizes, int n_in,
                              void* d_out, int out_size, void* d_ws,
                              size_t ws_size, hipStream_t stream) {
  (void)in_sizes; (void)n_in; (void)out_size; (void)ws_size;
  const float* x = (const float*)d_in[0];
  const float* wq = (const float*)d_in[1];
  const float* wk = (const float*)d_in[2];
  const float* wv = (const float*)d_in[3];
  const float* wo = (const float*)d_in[4];
  const float* fc = (const float*)d_in[5];
  const float* fs = (const float*)d_in[6];
  float* out = (float*)d_out;

  ushort* xb = (ushort*)d_ws;               // 4096x1024
  ushort* wqkvT = xb + 4194304;             // 1536x1024
  ushort* woT = wqkvT + 1572864;            // 1024x1024
  ushort* qkv = woT + 1048576;              // 4096x1536
  ushort* qh = qkv + 6291456;               // 32x2048x64
  ushort* kh = qh + 4194304;                // 8x2048x64
  ushort* vTb = kh + 1048576;               // 8x64x2048
  ushort* ao = vTb + 1048576;               // 4096x1024

  cast_x<<<4096, 256, 0, stream>>>(x, xb);
  dim3 tb(32, 8);
  trans_w<<<dim3(32, 32), tb, 0, stream>>>(wq, wqkvT, 1024);
  trans_w<<<dim3(32, 8), tb, 0, stream>>>(wk, wqkvT + 1024 * 1024, 256);
  trans_w<<<dim3(32, 8), tb, 0, stream>>>(wv, wqkvT + 1280 * 1024, 256);
  trans_w<<<dim3(32, 32), tb, 0, stream>>>(wo, woT, 1024);
  gemm_bt<true><<<dim3(12, 32), 256, 0, stream>>>(xb, wqkvT, qkv, 4096, 1536, 1024);
  rope_qk<<<10240, 256, 0, stream>>>(qkv, fc, fs, qh, kh);
  vtrans<<<256, 256, 0, stream>>>(qkv, vTb);
  attn_fwd<<<dim3(32, 32), 256, 0, stream>>>(qh, kh, vTb, ao);
  gemm_bt<false><<<dim3(8, 32), 256, 0, stream>>>(ao, woT, out, 4096, 1024, 1024);
}

// Round 2
// 174.837 us; speedup vs baseline: 1.3371x; 1.3371x over previous
//
#include <hip/hip_runtime.h>

typedef short bf8 __attribute__((ext_vector_type(8)));   // 8 bf16 in 4 VGPRs
typedef float f32x4 __attribute__((ext_vector_type(4)));
typedef float f32x16 __attribute__((ext_vector_type(16)));
typedef int i32x4 __attribute__((ext_vector_type(4)));

__device__ __forceinline__ ushort f2b(float f) {
  unsigned x = __builtin_bit_cast(unsigned, f);
  unsigned r = (x + 0x7fffu + ((x >> 16) & 1u)) >> 16;
  return (ushort)r;
}
__device__ __forceinline__ float b2f(ushort u) {
  unsigned x = ((unsigned)u) << 16;
  return __builtin_bit_cast(float, x);
}

__device__ __forceinline__ f32x4 mfma16(bf8 a, bf8 b, f32x4 c) {
  return __builtin_amdgcn_mfma_f32_16x16x32_bf16(a, b, c, 0, 0, 0);
}
__device__ __forceinline__ f32x16 mfma32(bf8 a, bf8 b, f32x16 c) {
  return __builtin_amdgcn_mfma_f32_32x32x16_bf16(a, b, c, 0, 0, 0);
}

__device__ __forceinline__ float fexp2(float x) {
#if __has_builtin(__builtin_amdgcn_exp2f)
  return __builtin_amdgcn_exp2f(x);
#else
  return exp2f(x);
#endif
}

__device__ __forceinline__ uint cvtpk(float lo, float hi_) {
  uint r;
  asm("v_cvt_pk_bf16_f32 %0, %1, %2" : "=v"(r) : "v"(lo), "v"(hi_));
  return r;
}
__device__ __forceinline__ void plswap(uint& a, uint& b) {
  asm("v_permlane32_swap_b32 %0, %1" : "+v"(a), "+v"(b));
}

__device__ __forceinline__ void gload16(const ushort* g, ushort* l) {
  __builtin_amdgcn_global_load_lds(
      (const __attribute__((address_space(1))) void*)g,
      (__attribute__((address_space(3))) void*)l, 16, 0, 0);
}

// ---------------- cast x (f32 -> bf16) ----------------
__global__ __launch_bounds__(256) void cast_x(const float* __restrict__ in,
                                              ushort* __restrict__ out) {
  const int i = (blockIdx.x * 256 + threadIdx.x) * 4;
  float4 v = *(const float4*)(in + i);
  ushort4 o;
  o.x = f2b(v.x); o.y = f2b(v.y); o.z = f2b(v.z); o.w = f2b(v.w);
  *(ushort4*)(out + i) = o;
}

// ------- transpose weight [K=1024][N] f32 -> [N][1024] bf16 -------
__global__ void trans_w(const float* __restrict__ in, ushort* __restrict__ out,
                        int N) {
  __shared__ float tile[32][33];
  const int kx = blockIdx.x * 32, nx = blockIdx.y * 32;
  const int tx = threadIdx.x, ty = threadIdx.y;
#pragma unroll
  for (int i = ty; i < 32; i += 8)
    tile[i][tx] = in[(size_t)(kx + i) * N + nx + tx];
  __syncthreads();
#pragma unroll
  for (int i = ty; i < 32; i += 8)
    out[(size_t)(nx + i) * 1024 + kx + tx] = f2b(tile[tx][i]);
}

// ---------------- GEMM C[M][N] = A[M][K] * Bt[N][K]^T ----------------
template <bool OUT_BF16>
__global__ __launch_bounds__(256) void gemm_bt(const ushort* __restrict__ A,
                                               const ushort* __restrict__ Bt,
                                               void* __restrict__ Cv, int M,
                                               int N, int K) {
  __shared__ ushort aL[128 * 32];
  __shared__ ushort bL[128 * 32];
  const int tid = threadIdx.x;
  const int wid = tid >> 6, lane = tid & 63;
  const int l15 = lane & 15, l4 = lane >> 4;
  const int bm = blockIdx.y * 128, bn = blockIdx.x * 128;
  const int wr = (wid >> 1) * 64, wc = (wid & 1) * 64;
  f32x4 acc[4][4] = {};
  for (int kb = 0; kb < K; kb += 32) {
    __syncthreads();
#pragma unroll
    for (int i = 0; i < 2; ++i) {
      const int e = (i * 256 + tid) * 8;
      const int r = e >> 5, c = e & 31;
      gload16(A + (size_t)(bm + r) * K + kb + c, &aL[i * 2048 + wid * 512]);
      gload16(Bt + (size_t)(bn + r) * K + kb + c, &bL[i * 2048 + wid * 512]);
    }
    asm volatile("s_waitcnt vmcnt(0)" ::: "memory");
    __syncthreads();
    bf8 af[4], bfr[4];
#pragma unroll
    for (int i = 0; i < 4; ++i) {
      af[i] = *(const bf8*)&aL[(wr + i * 16 + l15) * 32 + l4 * 8];
      bfr[i] = *(const bf8*)&bL[(wc + i * 16 + l15) * 32 + l4 * 8];
    }
#pragma unroll
    for (int i = 0; i < 4; ++i)
#pragma unroll
      for (int j = 0; j < 4; ++j)
        acc[i][j] = mfma16(af[i], bfr[j], acc[i][j]);
  }
#pragma unroll
  for (int i = 0; i < 4; ++i)
#pragma unroll
    for (int j = 0; j < 4; ++j)
#pragma unroll
      for (int r = 0; r < 4; ++r) {
        const size_t row = bm + wr + i * 16 + l4 * 4 + r;
        const size_t col = bn + wc + j * 16 + l15;
        if constexpr (OUT_BF16)
          ((ushort*)Cv)[row * N + col] = f2b(acc[i][j][r]);
        else
          ((float*)Cv)[row * N + col] = acc[i][j][r];
      }
}

// ---------------- RoPE for Q,K (reads fused qkv bf16) ----------------
// Q is pre-scaled by 0.125*log2(e) so attention scores are in log2 domain.
__global__ __launch_bounds__(256) void rope_qk(const ushort* __restrict__ qkv,
                                               const float* __restrict__ fc,
                                               const float* __restrict__ fs,
                                               ushort* __restrict__ qh,
                                               ushort* __restrict__ kh) {
  const int idx = blockIdx.x * 256 + threadIdx.x;  // 4096*640 total
  const int u = idx % 640;
  const int m = idx / 640;
  const int s = m & 2047, b = m >> 11;
  int col, j;
  if (u < 512) {
    j = u & 31;
    col = (u >> 5) * 64 + 2 * j;
  } else {
    j = (u - 512) & 31;
    col = 1024 + ((u - 512) >> 5) * 64 + 2 * j;
  }
  const uint pr = *(const uint*)(qkv + (size_t)m * 1536 + col);
  const float tr = b2f((ushort)(pr & 0xffff));
  const float ti = b2f((ushort)(pr >> 16));
  const float c = fc[s * 32 + j], sn = fs[s * 32 + j];
  float orr = tr * c - ti * sn;
  float oi = tr * sn + ti * c;
  if (u < 512) {
    orr *= 0.18033688f;  // (1/sqrt(64)) * log2(e)
    oi *= 0.18033688f;
    const uint w = (uint)f2b(orr) | ((uint)f2b(oi) << 16);
    *(uint*)(qh + ((size_t)(b * 16 + (u >> 5)) * 2048 + s) * 64 + 2 * j) = w;
  } else {
    const uint w = (uint)f2b(orr) | ((uint)f2b(oi) << 16);
    const int kv = (u - 512) >> 5;
    *(uint*)(kh + ((size_t)(b * 4 + kv) * 2048 + s) * 64 + 2 * j) = w;
  }
}

// ---------------- V transpose: qkv cols 1280.. -> vT[b*4+kv][64][2048] ----
__global__ __launch_bounds__(256) void vtrans(const ushort* __restrict__ qkv,
                                              ushort* __restrict__ vT) {
  __shared__ ushort tile[64][65];
  const int id = blockIdx.x;  // B*KVH*32 = 256
  const int st = id & 31, kv = (id >> 5) & 3, b = id >> 7;
  const int tid = threadIdx.x;
  for (int e = tid; e < 4096; e += 256) {
    const int r = e >> 6, c = e & 63;
    tile[r][c] =
        qkv[(size_t)(b * 2048 + st * 64 + r) * 1536 + 1280 + kv * 64 + c];
  }
  __syncthreads();
  for (int e = tid; e < 4096; e += 256) {
    const int d = e >> 6, c = e & 63;
    vT[((size_t)(b * 4 + kv) * 64 + d) * 2048 + st * 64 + c] = tile[c][d];
  }
}

// ---------------- Flash attention (causal, GQA), 32x32 swapped MFMA ------
// grid: (B*H=32, S/128=16), block 256 = 4 waves; wave w: 32 q rows.
// S^T = mfma(K, Q): lane holds q = lane&31, 16 keys at crow(r,hi).
// O^T = mfma(V^T, P^T): lane holds q = lane&31, d = dt*32 + crow(r,hi).
__global__ __launch_bounds__(256) void attn_fwd(const ushort* __restrict__ qh,
                                                const ushort* __restrict__ kh,
                                                const ushort* __restrict__ vT,
                                                ushort* __restrict__ ao) {
  __shared__ ushort olds[4][32 * 68];
  const int tid = threadIdx.x;
  const int wid = tid >> 6, lane = tid & 63;
  const int l31 = lane & 31, hi = lane >> 5;
  const int bh = blockIdx.x;
  const int b = bh >> 4, h = bh & 15;
  const int kv = h >> 2;
  const int qw = blockIdx.y * 128 + wid * 32;  // wave's q base
  const int qg = qw + l31;                     // this lane's q row

  // Q B-fragments: [n=q=lane&31][k=ks*16+hi*8+e]
  const ushort* qbase = qh + ((size_t)bh * 2048 + qg) * 64 + hi * 8;
  bf8 qf[4];
#pragma unroll
  for (int ks = 0; ks < 4; ++ks) qf[ks] = *(const bf8*)(qbase + ks * 16);

  const ushort* kbase = kh + (size_t)(b * 4 + kv) * 2048 * 64;
  const ushort* vbase = vT + (size_t)(b * 4 + kv) * 64 * 2048;

  f32x16 accO[2] = {};
  float m = -3e38f, l = 0.f;

  const int nkb = (qw + 95) >> 6;  // ceil((qw+32)/64)
  for (int kb = 0; kb < nkb; ++kb) {
    const int k0 = kb * 64;
    // ---- QK^T (swapped): A = K rows, B = Q ----
    f32x16 s0 = {}, s1 = {};
#pragma unroll
    for (int ks = 0; ks < 4; ++ks) {
      const bf8 kf0 =
          *(const bf8*)(kbase + (size_t)(k0 + l31) * 64 + ks * 16 + hi * 8);
      s0 = mfma32(kf0, qf[ks], s0);
    }
#pragma unroll
    for (int ks = 0; ks < 4; ++ks) {
      const bf8 kf1 = *(const bf8*)(kbase + (size_t)(k0 + 32 + l31) * 64 +
                                    ks * 16 + hi * 8);
      s1 = mfma32(kf1, qf[ks], s1);
    }
    // ---- issue V loads early (consumed after softmax) ----
    bf8 vf[2][4];
#pragma unroll
    for (int dt = 0; dt < 2; ++dt)
#pragma unroll
      for (int ks = 0; ks < 4; ++ks)
        vf[dt][ks] = *(const bf8*)(vbase + (size_t)(dt * 32 + l31) * 2048 +
                                   k0 + ks * 16 + hi * 8);
    // ---- causal mask (only last tile crosses diagonal) ----
    if (kb == nkb - 1) {
#pragma unroll
      for (int r = 0; r < 16; ++r) {
        const int key = k0 + (r & 3) + 8 * (r >> 2) + 4 * hi;
        if (key > qg) s0[r] = -1e30f;
        if (key + 32 > qg) s1[r] = -1e30f;
      }
    }
    // ---- online softmax (log2 domain), stats lane-local per q ----
    float t[16];
#pragma unroll
    for (int r = 0; r < 16; ++r) t[r] = fmaxf(s0[r], s1[r]);
#pragma unroll
    for (int st = 8; st > 0; st >>= 1)
#pragma unroll
      for (int r = 0; r < st; ++r) t[r] = fmaxf(t[r], t[r + st]);
    float mx = fmaxf(t[0], __shfl_xor(t[0], 32));
    const float mn = fmaxf(m, mx);
    const float scl = fexp2(m - mn);
    m = mn;
#pragma unroll
    for (int r = 0; r < 16; ++r) {
      s0[r] = fexp2(s0[r] - m);
      s1[r] = fexp2(s1[r] - m);
      t[r] = s0[r] + s1[r];
    }
#pragma unroll
    for (int st = 8; st > 0; st >>= 1)
#pragma unroll
      for (int r = 0; r < st; ++r) t[r] += t[r + st];
    const float rs = t[0] + __shfl_xor(t[0], 32);
    l = l * scl + rs;
#pragma unroll
    for (int e = 0; e < 16; ++e) {
      accO[0][e] *= scl;
      accO[1][e] *= scl;
    }
    // ---- P -> bf16 A/B fragments via cvt_pk + permlane32_swap ----
    bf8 pa[4];
    {
      uint a0 = cvtpk(s0[0], s0[1]), a1 = cvtpk(s0[2], s0[3]);
      uint b0 = cvtpk(s0[4], s0[5]), b1 = cvtpk(s0[6], s0[7]);
      plswap(a0, b0);
      plswap(a1, b1);
      i32x4 w = {(int)a0, (int)a1, (int)b0, (int)b1};
      pa[0] = __builtin_bit_cast(bf8, w);
      uint c0 = cvtpk(s0[8], s0[9]), c1 = cvtpk(s0[10], s0[11]);
      uint d0 = cvtpk(s0[12], s0[13]), d1 = cvtpk(s0[14], s0[15]);
      plswap(c0, d0);
      plswap(c1, d1);
      i32x4 w2 = {(int)c0, (int)c1, (int)d0, (int)d1};
      pa[1] = __builtin_bit_cast(bf8, w2);
    }
    {
      uint a0 = cvtpk(s1[0], s1[1]), a1 = cvtpk(s1[2], s1[3]);
      uint b0 = cvtpk(s1[4], s1[5]), b1 = cvtpk(s1[6], s1[7]);
      plswap(a0, b0);
      plswap(a1, b1);
      i32x4 w = {(int)a0, (int)a1, (int)b0, (int)b1};
      pa[2] = __builtin_bit_cast(bf8, w);
      uint c0 = cvtpk(s1[8], s1[9]), c1 = cvtpk(s1[10], s1[11]);
      uint d0 = cvtpk(s1[12], s1[13]), d1 = cvtpk(s1[14], s1[15]);
      plswap(c0, d0);
      plswap(c1, d1);
      i32x4 w2 = {(int)c0, (int)c1, (int)d0, (int)d1};
      pa[3] = __builtin_bit_cast(bf8, w2);
    }
    // ---- PV (double-swapped): O^T += V^T * P^T ----
#pragma unroll
    for (int dt = 0; dt < 2; ++dt)
#pragma unroll
      for (int ks = 0; ks < 4; ++ks)
        accO[dt] = mfma32(vf[dt][ks], pa[ks], accO[dt]);
  }
  // ---- epilogue: divide by l, transpose O^T->O via LDS, coalesced store ----
  const float inv = 1.0f / l;
  ushort* myl = olds[wid];
#pragma unroll
  for (int dt = 0; dt < 2; ++dt)
#pragma unroll
    for (int rq = 0; rq < 4; ++rq) {
      uint2 w;
      w.x = (uint)f2b(accO[dt][rq * 4 + 0] * inv) |
            ((uint)f2b(accO[dt][rq * 4 + 1] * inv) << 16);
      w.y = (uint)f2b(accO[dt][rq * 4 + 2] * inv) |
            ((uint)f2b(accO[dt][rq * 4 + 3] * inv) << 16);
      const int d = dt * 32 + 8 * rq + 4 * hi;
      *(uint2*)&myl[l31 * 68 + d] = w;
    }
  asm volatile("s_waitcnt lgkmcnt(0)" ::: "memory");
  __builtin_amdgcn_sched_barrier(0);
  const int rrow = lane >> 4;
  const int rcol = (lane & 15) * 4;
  const size_t gbase = ((size_t)b * 2048 + qw) * 1024 + h * 64;
#pragma unroll
  for (int i = 0; i < 8; ++i) {
    const int rw = i * 4 + rrow;
    uint2 v = *(const uint2*)&myl[rw * 68 + rcol];
    *(uint2*)&ao[gbase + (size_t)rw * 1024 + rcol] = v;
  }
}

extern "C" void kernel_launch(void* const* d_in, const int* in_sizes, int n_in,
                              void* d_out, int out_size, void* d_ws,
                              size_t ws_size, hipStream_t stream) {
  (void)in_sizes; (void)n_in; (void)out_size; (void)ws_size;
  const float* x = (const float*)d_in[0];
  const float* wq = (const float*)d_in[1];
  const float* wk = (const float*)d_in[2];
  const float* wv = (const float*)d_in[3];
  const float* wo = (const float*)d_in[4];
  const float* fc = (const float*)d_in[5];
  const float* fs = (const float*)d_in[6];
  float* out = (float*)d_out;

  ushort* xb = (ushort*)d_ws;               // 4096x1024
  ushort* wqkvT = xb + 4194304;             // 1536x1024
  ushort* woT = wqkvT + 1572864;            // 1024x1024
  ushort* qkv = woT + 1048576;              // 4096x1536
  ushort* qh = qkv + 6291456;               // 32x2048x64
  ushort* kh = qh + 4194304;                // 8x2048x64
  ushort* vTb = kh + 1048576;               // 8x64x2048
  ushort* ao = vTb + 1048576;               // 4096x1024

  cast_x<<<4096, 256, 0, stream>>>(x, xb);
  dim3 tb(32, 8);
  trans_w<<<dim3(32, 32), tb, 0, stream>>>(wq, wqkvT, 1024);
  trans_w<<<dim3(32, 8), tb, 0, stream>>>(wk, wqkvT + 1024 * 1024, 256);
  trans_w<<<dim3(32, 8), tb, 0, stream>>>(wv, wqkvT + 1280 * 1024, 256);
  trans_w<<<dim3(32, 32), tb, 0, stream>>>(wo, woT, 1024);
  gemm_bt<true><<<dim3(12, 32), 256, 0, stream>>>(xb, wqkvT, qkv, 4096, 1536, 1024);
  rope_qk<<<10240, 256, 0, stream>>>(qkv, fc, fs, qh, kh);
  vtrans<<<256, 256, 0, stream>>>(qkv, vTb);
  attn_fwd<<<dim3(32, 16), 256, 0, stream>>>(qh, kh, vTb, ao);
  gemm_bt<false><<<dim3(8, 32), 256, 0, stream>>>(ao, woT, out, 4096, 1024, 1024);
}

// Round 3
// 164.557 us; speedup vs baseline: 1.4206x; 1.0625x over previous
//
#include <hip/hip_runtime.h>

typedef short bf8 __attribute__((ext_vector_type(8)));   // 8 bf16 in 4 VGPRs
typedef float f32x4 __attribute__((ext_vector_type(4)));
typedef float f32x16 __attribute__((ext_vector_type(16)));
typedef int i32x4 __attribute__((ext_vector_type(4)));

__device__ __forceinline__ ushort f2b(float f) {
  unsigned x = __builtin_bit_cast(unsigned, f);
  unsigned r = (x + 0x7fffu + ((x >> 16) & 1u)) >> 16;
  return (ushort)r;
}
__device__ __forceinline__ float b2f(ushort u) {
  unsigned x = ((unsigned)u) << 16;
  return __builtin_bit_cast(float, x);
}

__device__ __forceinline__ f32x4 mfma16(bf8 a, bf8 b, f32x4 c) {
  return __builtin_amdgcn_mfma_f32_16x16x32_bf16(a, b, c, 0, 0, 0);
}
__device__ __forceinline__ f32x16 mfma32(bf8 a, bf8 b, f32x16 c) {
  return __builtin_amdgcn_mfma_f32_32x32x16_bf16(a, b, c, 0, 0, 0);
}

__device__ __forceinline__ float fexp2(float x) {
#if __has_builtin(__builtin_amdgcn_exp2f)
  return __builtin_amdgcn_exp2f(x);
#else
  return exp2f(x);
#endif
}

__device__ __forceinline__ uint cvtpk(float lo, float hi_) {
  uint r;
  asm("v_cvt_pk_bf16_f32 %0, %1, %2" : "=v"(r) : "v"(lo), "v"(hi_));
  return r;
}
__device__ __forceinline__ void plswap(uint& a, uint& b) {
  asm("v_permlane32_swap_b32 %0, %1" : "+v"(a), "+v"(b));
}

__device__ __forceinline__ void gload16(const ushort* g, ushort* l) {
  __builtin_amdgcn_global_load_lds(
      (const __attribute__((address_space(1))) void*)g,
      (__attribute__((address_space(3))) void*)l, 16, 0, 0);
}

// ---------------- cast x (f32 -> bf16) ----------------
__global__ __launch_bounds__(256) void cast_x(const float* __restrict__ in,
                                              ushort* __restrict__ out) {
  const int i = (blockIdx.x * 256 + threadIdx.x) * 4;
  float4 v = *(const float4*)(in + i);
  ushort4 o;
  o.x = f2b(v.x); o.y = f2b(v.y); o.z = f2b(v.z); o.w = f2b(v.w);
  *(ushort4*)(out + i) = o;
}

// ------- transpose weight [K=1024][N] f32 -> [N][1024] bf16 -------
__global__ void trans_w(const float* __restrict__ in, ushort* __restrict__ out,
                        int N) {
  __shared__ float tile[32][33];
  const int kx = blockIdx.x * 32, nx = blockIdx.y * 32;
  const int tx = threadIdx.x, ty = threadIdx.y;
#pragma unroll
  for (int i = ty; i < 32; i += 8)
    tile[i][tx] = in[(size_t)(kx + i) * N + nx + tx];
  __syncthreads();
#pragma unroll
  for (int i = ty; i < 32; i += 8)
    out[(size_t)(nx + i) * 1024 + kx + tx] = f2b(tile[tx][i]);
}

// ---------------- GEMM C[M][N] = A[M][K] * Bt[N][K]^T ----------------
template <bool OUT_BF16>
__global__ __launch_bounds__(256) void gemm_bt(const ushort* __restrict__ A,
                                               const ushort* __restrict__ Bt,
                                               void* __restrict__ Cv, int M,
                                               int N, int K) {
  __shared__ ushort aL[128 * 32];
  __shared__ ushort bL[128 * 32];
  const int tid = threadIdx.x;
  const int wid = tid >> 6, lane = tid & 63;
  const int l15 = lane & 15, l4 = lane >> 4;
  const int bm = blockIdx.y * 128, bn = blockIdx.x * 128;
  const int wr = (wid >> 1) * 64, wc = (wid & 1) * 64;
  f32x4 acc[4][4] = {};
  for (int kb = 0; kb < K; kb += 32) {
    __syncthreads();
#pragma unroll
    for (int i = 0; i < 2; ++i) {
      const int e = (i * 256 + tid) * 8;
      const int r = e >> 5, c = e & 31;
      gload16(A + (size_t)(bm + r) * K + kb + c, &aL[i * 2048 + wid * 512]);
      gload16(Bt + (size_t)(bn + r) * K + kb + c, &bL[i * 2048 + wid * 512]);
    }
    asm volatile("s_waitcnt vmcnt(0)" ::: "memory");
    __syncthreads();
    bf8 af[4], bfr[4];
#pragma unroll
    for (int i = 0; i < 4; ++i) {
      af[i] = *(const bf8*)&aL[(wr + i * 16 + l15) * 32 + l4 * 8];
      bfr[i] = *(const bf8*)&bL[(wc + i * 16 + l15) * 32 + l4 * 8];
    }
#pragma unroll
    for (int i = 0; i < 4; ++i)
#pragma unroll
      for (int j = 0; j < 4; ++j)
        acc[i][j] = mfma16(af[i], bfr[j], acc[i][j]);
  }
#pragma unroll
  for (int i = 0; i < 4; ++i)
#pragma unroll
    for (int j = 0; j < 4; ++j)
#pragma unroll
      for (int r = 0; r < 4; ++r) {
        const size_t row = bm + wr + i * 16 + l4 * 4 + r;
        const size_t col = bn + wc + j * 16 + l15;
        if constexpr (OUT_BF16)
          ((ushort*)Cv)[row * N + col] = f2b(acc[i][j][r]);
        else
          ((float*)Cv)[row * N + col] = acc[i][j][r];
      }
}

// ---------------- RoPE for Q,K (reads fused qkv bf16) ----------------
// Q is pre-scaled by 0.125*log2(e) so attention scores are in log2 domain.
__global__ __launch_bounds__(256) void rope_qk(const ushort* __restrict__ qkv,
                                               const float* __restrict__ fc,
                                               const float* __restrict__ fs,
                                               ushort* __restrict__ qh,
                                               ushort* __restrict__ kh) {
  const int idx = blockIdx.x * 256 + threadIdx.x;  // 4096*640 total
  const int u = idx % 640;
  const int m = idx / 640;
  const int s = m & 2047, b = m >> 11;
  int col, j;
  if (u < 512) {
    j = u & 31;
    col = (u >> 5) * 64 + 2 * j;
  } else {
    j = (u - 512) & 31;
    col = 1024 + ((u - 512) >> 5) * 64 + 2 * j;
  }
  const uint pr = *(const uint*)(qkv + (size_t)m * 1536 + col);
  const float tr = b2f((ushort)(pr & 0xffff));
  const float ti = b2f((ushort)(pr >> 16));
  const float c = fc[s * 32 + j], sn = fs[s * 32 + j];
  float orr = tr * c - ti * sn;
  float oi = tr * sn + ti * c;
  if (u < 512) {
    orr *= 0.18033688f;  // (1/sqrt(64)) * log2(e)
    oi *= 0.18033688f;
    const uint w = (uint)f2b(orr) | ((uint)f2b(oi) << 16);
    *(uint*)(qh + ((size_t)(b * 16 + (u >> 5)) * 2048 + s) * 64 + 2 * j) = w;
  } else {
    const uint w = (uint)f2b(orr) | ((uint)f2b(oi) << 16);
    const int kv = (u - 512) >> 5;
    *(uint*)(kh + ((size_t)(b * 4 + kv) * 2048 + s) * 64 + 2 * j) = w;
  }
}

// ---------------- V transpose: qkv cols 1280.. -> vT[b*4+kv][64][2048] ----
__global__ __launch_bounds__(256) void vtrans(const ushort* __restrict__ qkv,
                                              ushort* __restrict__ vT) {
  __shared__ ushort tile[64][65];
  const int id = blockIdx.x;  // B*KVH*32 = 256
  const int st = id & 31, kv = (id >> 5) & 3, b = id >> 7;
  const int tid = threadIdx.x;
  for (int e = tid; e < 4096; e += 256) {
    const int r = e >> 6, c = e & 63;
    tile[r][c] =
        qkv[(size_t)(b * 2048 + st * 64 + r) * 1536 + 1280 + kv * 64 + c];
  }
  __syncthreads();
  for (int e = tid; e < 4096; e += 256) {
    const int d = e >> 6, c = e & 63;
    vT[((size_t)(b * 4 + kv) * 64 + d) * 2048 + st * 64 + c] = tile[c][d];
  }
}

// ---------------- Flash attention (causal, GQA), 32x32 swapped MFMA ------
// 2048 one-wave blocks; block -> (bh, qtile) with complement pairing so
// adjacent blocks have complementary causal work (load balance).
// S^T = mfma(K, Q): lane holds q = lane&31, 16 keys at crow(r,hi).
// O^T = mfma(V^T, P^T): lane holds q = lane&31, d = dt*32 + crow(r,hi).
struct KV {
  bf8 k[8];
  bf8 v[8];
};

__device__ __forceinline__ void loadkv(KV& d, const ushort* kbase,
                                       const ushort* vbase, int k0, int l31,
                                       int hi) {
#pragma unroll
  for (int ks = 0; ks < 4; ++ks) {
    d.k[ks] = *(const bf8*)(kbase + (size_t)(k0 + l31) * 64 + ks * 16 + hi * 8);
    d.k[4 + ks] =
        *(const bf8*)(kbase + (size_t)(k0 + 32 + l31) * 64 + ks * 16 + hi * 8);
    d.v[ks] = *(const bf8*)(vbase + (size_t)l31 * 2048 + k0 + ks * 16 + hi * 8);
    d.v[4 + ks] =
        *(const bf8*)(vbase + (size_t)(32 + l31) * 2048 + k0 + ks * 16 + hi * 8);
  }
}

__device__ __forceinline__ void astep(const KV& kvb, const bf8 (&qf)[4],
                                      f32x16& o0, f32x16& o1, float& m,
                                      float& l, int k0, int qg, bool maskt,
                                      int hi) {
  f32x16 s0 = {}, s1 = {};
#pragma unroll
  for (int ks = 0; ks < 4; ++ks) s0 = mfma32(kvb.k[ks], qf[ks], s0);
#pragma unroll
  for (int ks = 0; ks < 4; ++ks) s1 = mfma32(kvb.k[4 + ks], qf[ks], s1);
  if (maskt) {
#pragma unroll
    for (int r = 0; r < 16; ++r) {
      const int key = k0 + (r & 3) + 8 * (r >> 2) + 4 * hi;
      if (key > qg) s0[r] = -1e30f;
      if (key + 32 > qg) s1[r] = -1e30f;
    }
  }
  float t[16];
#pragma unroll
  for (int r = 0; r < 16; ++r) t[r] = fmaxf(s0[r], s1[r]);
#pragma unroll
  for (int st = 8; st > 0; st >>= 1)
#pragma unroll
    for (int r = 0; r < st; ++r) t[r] = fmaxf(t[r], t[r + st]);
  const float mx = fmaxf(t[0], __shfl_xor(t[0], 32));
  const float mn = fmaxf(m, mx);
  const float scl = fexp2(m - mn);
  m = mn;
#pragma unroll
  for (int r = 0; r < 16; ++r) {
    s0[r] = fexp2(s0[r] - m);
    s1[r] = fexp2(s1[r] - m);
    t[r] = s0[r] + s1[r];
  }
#pragma unroll
  for (int st = 8; st > 0; st >>= 1)
#pragma unroll
    for (int r = 0; r < st; ++r) t[r] += t[r + st];
  const float rs = t[0] + __shfl_xor(t[0], 32);
  l = l * scl + rs;
#pragma unroll
  for (int e = 0; e < 16; ++e) {
    o0[e] *= scl;
    o1[e] *= scl;
  }
  bf8 pa[4];
  {
    uint a0 = cvtpk(s0[0], s0[1]), a1 = cvtpk(s0[2], s0[3]);
    uint b0 = cvtpk(s0[4], s0[5]), b1 = cvtpk(s0[6], s0[7]);
    plswap(a0, b0);
    plswap(a1, b1);
    i32x4 w = {(int)a0, (int)a1, (int)b0, (int)b1};
    pa[0] = __builtin_bit_cast(bf8, w);
    uint c0 = cvtpk(s0[8], s0[9]), c1 = cvtpk(s0[10], s0[11]);
    uint d0 = cvtpk(s0[12], s0[13]), d1 = cvtpk(s0[14], s0[15]);
    plswap(c0, d0);
    plswap(c1, d1);
    i32x4 w2 = {(int)c0, (int)c1, (int)d0, (int)d1};
    pa[1] = __builtin_bit_cast(bf8, w2);
  }
  {
    uint a0 = cvtpk(s1[0], s1[1]), a1 = cvtpk(s1[2], s1[3]);
    uint b0 = cvtpk(s1[4], s1[5]), b1 = cvtpk(s1[6], s1[7]);
    plswap(a0, b0);
    plswap(a1, b1);
    i32x4 w = {(int)a0, (int)a1, (int)b0, (int)b1};
    pa[2] = __builtin_bit_cast(bf8, w);
    uint c0 = cvtpk(s1[8], s1[9]), c1 = cvtpk(s1[10], s1[11]);
    uint d0 = cvtpk(s1[12], s1[13]), d1 = cvtpk(s1[14], s1[15]);
    plswap(c0, d0);
    plswap(c1, d1);
    i32x4 w2 = {(int)c0, (int)c1, (int)d0, (int)d1};
    pa[3] = __builtin_bit_cast(bf8, w2);
  }
#pragma unroll
  for (int ks = 0; ks < 4; ++ks) o0 = mfma32(kvb.v[ks], pa[ks], o0);
#pragma unroll
  for (int ks = 0; ks < 4; ++ks) o1 = mfma32(kvb.v[4 + ks], pa[ks], o1);
}

__global__ __launch_bounds__(64) void attn_fwd(const ushort* __restrict__ qh,
                                               const ushort* __restrict__ kh,
                                               const ushort* __restrict__ vT,
                                               ushort* __restrict__ ao) {
  __shared__ ushort olds[32 * 68];
  const int lane = threadIdx.x;
  const int l31 = lane & 31, hi = lane >> 5;
  const int gid = blockIdx.x;  // 2048
  const int bh = gid & 31;
  const int u = gid >> 5;
  const int t = (u & 1) ? (63 - (u >> 1)) : (u >> 1);
  const int b = bh >> 4, h = bh & 15;
  const int kv = h >> 2;
  const int qw = t * 32;
  const int qg = qw + l31;

  const ushort* qbase = qh + ((size_t)bh * 2048 + qg) * 64 + hi * 8;
  bf8 qf[4];
#pragma unroll
  for (int ks = 0; ks < 4; ++ks) qf[ks] = *(const bf8*)(qbase + ks * 16);

  const ushort* kbase = kh + (size_t)(b * 4 + kv) * 2048 * 64;
  const ushort* vbase = vT + (size_t)(b * 4 + kv) * 64 * 2048;

  f32x16 o0 = {}, o1 = {};
  float m = -3e38f, l = 0.f;

  const int nkb = (qw + 95) >> 6;  // ceil((qw+32)/64)

  KV bufA, bufB;
  loadkv(bufA, kbase, vbase, 0, l31, hi);
  int kb = 0;
  for (;;) {
    if (kb + 1 < nkb) loadkv(bufB, kbase, vbase, (kb + 1) * 64, l31, hi);
    astep(bufA, qf, o0, o1, m, l, kb * 64, qg, kb == nkb - 1, hi);
    if (++kb == nkb) break;
    if (kb + 1 < nkb) loadkv(bufA, kbase, vbase, (kb + 1) * 64, l31, hi);
    astep(bufB, qf, o0, o1, m, l, kb * 64, qg, kb == nkb - 1, hi);
    if (++kb == nkb) break;
  }

  // ---- epilogue: divide by l, transpose O^T->O via LDS, coalesced store ----
  const float inv = 1.0f / l;
#pragma unroll
  for (int dt = 0; dt < 2; ++dt)
#pragma unroll
    for (int rq = 0; rq < 4; ++rq) {
      const f32x16& ac = dt ? o1 : o0;
      uint2 w;
      w.x = (uint)f2b(ac[rq * 4 + 0] * inv) |
            ((uint)f2b(ac[rq * 4 + 1] * inv) << 16);
      w.y = (uint)f2b(ac[rq * 4 + 2] * inv) |
            ((uint)f2b(ac[rq * 4 + 3] * inv) << 16);
      const int d = dt * 32 + 8 * rq + 4 * hi;
      *(uint2*)&olds[l31 * 68 + d] = w;
    }
  asm volatile("s_waitcnt lgkmcnt(0)" ::: "memory");
  __builtin_amdgcn_sched_barrier(0);
  const int rrow = lane >> 4;
  const int rcol = (lane & 15) * 4;
  const size_t gbase = ((size_t)b * 2048 + qw) * 1024 + h * 64;
#pragma unroll
  for (int i = 0; i < 8; ++i) {
    const int rw = i * 4 + rrow;
    uint2 v = *(const uint2*)&olds[rw * 68 + rcol];
    *(uint2*)&ao[gbase + (size_t)rw * 1024 + rcol] = v;
  }
}

extern "C" void kernel_launch(void* const* d_in, const int* in_sizes, int n_in,
                              void* d_out, int out_size, void* d_ws,
                              size_t ws_size, hipStream_t stream) {
  (void)in_sizes; (void)n_in; (void)out_size; (void)ws_size;
  const float* x = (const float*)d_in[0];
  const float* wq = (const float*)d_in[1];
  const float* wk = (const float*)d_in[2];
  const float* wv = (const float*)d_in[3];
  const float* wo = (const float*)d_in[4];
  const float* fc = (const float*)d_in[5];
  const float* fs = (const float*)d_in[6];
  float* out = (float*)d_out;

  ushort* xb = (ushort*)d_ws;               // 4096x1024
  ushort* wqkvT = xb + 4194304;             // 1536x1024
  ushort* woT = wqkvT + 1572864;            // 1024x1024
  ushort* qkv = woT + 1048576;              // 4096x1536
  ushort* qh = qkv + 6291456;               // 32x2048x64
  ushort* kh = qh + 4194304;                // 8x2048x64
  ushort* vTb = kh + 1048576;               // 8x64x2048
  ushort* ao = vTb + 1048576;               // 4096x1024

  cast_x<<<4096, 256, 0, stream>>>(x, xb);
  dim3 tb(32, 8);
  trans_w<<<dim3(32, 32), tb, 0, stream>>>(wq, wqkvT, 1024);
  trans_w<<<dim3(32, 8), tb, 0, stream>>>(wk, wqkvT + 1024 * 1024, 256);
  trans_w<<<dim3(32, 8), tb, 0, stream>>>(wv, wqkvT + 1280 * 1024, 256);
  trans_w<<<dim3(32, 32), tb, 0, stream>>>(wo, woT, 1024);
  gemm_bt<true><<<dim3(12, 32), 256, 0, stream>>>(xb, wqkvT, qkv, 4096, 1536, 1024);
  rope_qk<<<10240, 256, 0, stream>>>(qkv, fc, fs, qh, kh);
  vtrans<<<256, 256, 0, stream>>>(qkv, vTb);
  attn_fwd<<<2048, 64, 0, stream>>>(qh, kh, vTb, ao);
  gemm_bt<false><<<dim3(8, 32), 256, 0, stream>>>(ao, woT, out, 4096, 1024, 1024);
}